// Round 4
// baseline (87.900 us; speedup 1.0000x reference)
//
#include <hip/hip_runtime.h>

typedef __attribute__((ext_vector_type(4)))  short bf16x4;   // 4 bf16 = 2 VGPRs
typedef __attribute__((ext_vector_type(16))) float f32x16;   // MFMA 32x32 C/D

#define TPB    256
#define NPTS   8192
#define NB     4
#define TOTPTS (NB * NPTS)        // 32768
#define YTILE  1024               // y per block
#define NTILES (YTILE / 32)       // 32 MFMA tiles
#define GYB    (NPTS / YTILE)     // 8 y-chunks
#define NSLICE (2 * NB)           // 8 (dir,batch) slices per chunk
#define XW1    64                 // x per 1-wave block
#define GX1    (NPTS / XW1)       // 128 x-blocks
#define WS2_FLOATS ((size_t)GYB * NSLICE * NPTS)  // 512K floats = 2 MB
#define NPARTIAL ((2 * TOTPTS) / 64)   // 1024
#define FRAG_OFF_FLOATS ((size_t)(4 << 20) / 4)   // frag region at ws + 4 MB

// ---------------------------------------------------------------------------
// R24: structural attack — LDS-free 1-wave blocks + precomputed fragments.
// R21 (reg diet) neutral, R22 (lb(256,4)) miscompiled, R23 (builtin SW
// pipeline) neutral: scheduling inside the 4-wave-LDS-block structure does
// not move nnmin (~27us vs ~5-6us issue floor: 0.9us MFMA + 3.6us min3).
// Surviving suspects are STRUCTURAL: __syncthreads + 16KB LDS + 4-wave
// block granularity + allocator ballooning past 128 VGPRs under lb(256,1)
// -> low waves/SIMD, batched blocks, exposed MFMA/LDS latency everywhere.
// This round removes all three at once:
//   prep_frags: builds all A-frags ONCE into ws (1 MB, L2-resident) —
//     staging bfr math ran 32x redundantly per y across x-blocks before.
//   nnmin_mfma1w: 8192 independent 64-thread blocks, NO LDS, NO barrier,
//     coalesced 8B frag loads (wave covers 512 contiguous B), distance-2
//     prefetch, single MFMA result pair (~80 VGPR live set). 1-wave blocks
//     pack at wave granularity: VGPR<=128 -> 4+ waves/SIMD naturally.
//   lb(64,1)/lb(256,1) only — NO VGPR caps (R14/R15/R22: forced-occupancy
//   launch_bounds miscompiles; that lever is dead).
// Numerics bit-identical to R18/R21/R23 (same frag math, min reassoc only):
// absmax must be exactly 0.01171875.
// Prior exhausted levers (kept):
//   forced-occupancy launch_bounds: R14/R15/R22 deterministic corruption.
//   hand-asm MFMA: R12 device-abort, R20 hazard corruption.
//   SW pipeline at source: R23 neutral. Tile scaling: R13 neutral.
//   Kernel fusion: R4/R19 fence/coherence tax. Packed fp32: R5/R6 dead.
// Structure: K=8 mfma_f32_32x32x8bf16_1k (8 K-slots: y compensated hi/lo +
// hy split; x bf16-rounded — finalize uses identically-rounded hx so
// d = |xh - y|, err ~0.01 < 0.036 threshold):
//   A (y, M) k: [yh0,yl0, yh1,yl1 | yh2,yl2, hyh,hyl]
//   B (x, N) k: [-xh0,-xh0, -xh1,-xh1 | -xh2,-xh2, 1,1]
// Combine: asm v_min3_f32 tree, 8 ops per 16 values (R10: plain fminf ->
// accvgpr churn; VOP3 cannot source AGPRs). Disjoint-slice plain stores,
// no atomics/init (R16). 4 launches: kernel boundary = cross-XCD flush.
// Budget: ~40us harness 0xAA ws-fill (sunk) + prep ~3 + nnmin (target
// ~10) + finalize/scalar/gaps ~13.
// ---------------------------------------------------------------------------

__device__ __forceinline__ short bfr(float f) {       // fp32->bf16 RNE
    unsigned u = __float_as_uint(f);
    return (short)((u + 0x7FFFu + ((u >> 16) & 1u)) >> 16);
}
__device__ __forceinline__ float bf2f(short s) {
    return __uint_as_float(((unsigned)(unsigned short)s) << 16);
}
__device__ __forceinline__ float min3f(float a, float b, float c) {
    float d;
    asm("v_min3_f32 %0, %1, %2, %3" : "=v"(d) : "v"(a), "v"(b), "v"(c));
    return d;
}
// 8-op tree: 16 values, one touch each (minimum), then fold into rm.
__device__ __forceinline__ void tree16(const f32x16& d, float& rm) {
    float u0 = min3f(d[0],  d[1],  d[2]);
    float u1 = min3f(d[3],  d[4],  d[5]);
    float u2 = min3f(d[6],  d[7],  d[8]);
    float u3 = min3f(d[9],  d[10], d[11]);
    float u4 = min3f(d[12], d[13], d[14]);
    float v0 = min3f(u0, u1, d[15]);
    float v1 = min3f(u2, u3, u4);
    asm("v_min3_f32 %0, %0, %1, %2" : "+v"(rm) : "v"(v0), "v"(v1));
}

// Build A-fragments for all 8 (dir,batch) slices: frag[s][j][half].
// grid = (NPTS/TPB, NSLICE) = (32, 8); one thread per (slice, y-point).
__global__ void __launch_bounds__(TPB, 1) prep_frags(
        const float* __restrict__ T, const float* __restrict__ P,
        bf16x4* __restrict__ frag)
{
    const int s   = blockIdx.y;
    const int dir = s >> 2;
    const int b   = s & 3;
    const float* Yb = (dir ? T : P) + (size_t)b * NPTS * 3;  // y-side of slice
    const int j = blockIdx.x * TPB + threadIdx.x;

    const float* yp = Yb + (size_t)j * 3;
    float y0 = yp[0], y1 = yp[1], y2 = yp[2];
    short yh0 = bfr(y0); short yl0 = bfr(y0 - bf2f(yh0));
    short yh1 = bfr(y1); short yl1 = bfr(y1 - bf2f(yh1));
    short yh2 = bfr(y2); short yl2 = bfr(y2 - bf2f(yh2));
    float hy  = 0.5f * (y0 * y0 + y1 * y1 + y2 * y2);
    short hyh = bfr(hy); short hyl = bfr(hy - bf2f(hyh));
    bf16x4 e0 = {yh0, yl0, yh1, yl1};   // k = 0..3  (lanes < 32)
    bf16x4 e1 = {yh2, yl2, hyh, hyl};   // k = 4..7  (lanes >= 32)
    size_t base = ((size_t)s * NPTS + j) * 2;
    frag[base]     = e0;
    frag[base + 1] = e1;
}

// grid = (GX1, GYB, 2*NB) = (128, 8, 8) = 8192 one-wave blocks.
// Wave owns 64 x (2 B-frags) and streams 32 A-frag tiles from global.
__global__ void __launch_bounds__(64, 1) nnmin_mfma1w(
        const float* __restrict__ T, const float* __restrict__ P,
        const bf16x4* __restrict__ frag, float* __restrict__ ws2)
{
    const int z   = blockIdx.z;
    const int dir = z >> 2;
    const int b   = z & 3;
    const float* Xb = (dir ? P : T) + (size_t)b * NPTS * 3;
    const int l     = threadIdx.x;     // lane (TPB = 64)
    const int ybase = blockIdx.y * YTILE;
    const int xw    = blockIdx.x * XW1;

    // ---- build the wave's 2 B-fragments: x bf16-rounded, negated ----
    const int   kh  = l >> 5;          // which K-half this lane supplies
    const short ONE = 0x3F80;          // bf16(1.0)
    bf16x4 B[2];
#pragma unroll
    for (int f = 0; f < 2; ++f) {
        const float* xp = Xb + (size_t)(xw + f * 32 + (l & 31)) * 3;
        short h0 = bfr(-xp[0]);        // RNE is sign-symmetric
        short h1 = bfr(-xp[1]);
        short h2 = bfr(-xp[2]);
        bf16x4 e;
        if (kh == 0) e = (bf16x4){h0, h0, h1, h1};
        else         e = (bf16x4){h2, h2, ONE, ONE};
        B[f] = e;
    }

    // ---- main loop: 1 coalesced 8B frag load + 2 MFMA + 17 min3 per tile --
    const bf16x4* fa = frag + ((size_t)z * NPTS + ybase) * 2;
    const int i0 = (l & 31) * 2 + kh;  // lane's element within a 512B tile row

    f32x16 zero = {0.f};               // loop-invariant C input
    float rm0 = 3.0e38f, rm1 = 3.0e38f;

    bf16x4 A0 = fa[i0];                // distance-2 prefetch pipeline
    bf16x4 A1 = fa[64 + i0];
#pragma unroll 1
    for (int tl = 0; tl < NTILES; ++tl) {
        bf16x4 An = fa[((tl + 2) & (NTILES - 1)) * 64 + i0];
        f32x16 da = __builtin_amdgcn_mfma_f32_32x32x8bf16_1k(A0, B[0], zero, 0, 0, 0);
        f32x16 db = __builtin_amdgcn_mfma_f32_32x32x8bf16_1k(A0, B[1], zero, 0, 0, 0);
        tree16(da, rm0);
        tree16(db, rm1);
        A0 = A1;
        A1 = An;
    }

    // ---- epilogue: cross-half min + plain store to own slice ----
    float* o = ws2 + ((size_t)blockIdx.y * NSLICE + z) * NPTS;
    {
        float v = fminf(rm0, __shfl_xor(rm0, 32, 64));  // rows split across halves
        if (l < 32) o[xw + l] = v;       // disjoint: no atomics, no init
    }
    {
        float v = fminf(rm1, __shfl_xor(rm1, 32, 64));
        if (l < 32) o[xw + 32 + l] = v;
    }
}

// Min-reduce 8 chunk slices, add hx(ROUNDED x), sqrt; mins_seeds; wave sums.
__global__ void __launch_bounds__(TPB) finalize_kernel(
        const float* __restrict__ ws2,
        const float* __restrict__ T, const float* __restrict__ P,
        float* __restrict__ out, float* __restrict__ partials)
{
    int i   = blockIdx.x * TPB + threadIdx.x;   // 0 .. 2*TOTPTS-1
    int dir = (i >= TOTPTS) ? 1 : 0;            // uniform per block
    int idx = i - dir * TOTPTS;
    int b   = idx >> 13;
    int x   = idx & (NPTS - 1);

    const float* p0 = ws2 + (size_t)(dir * 4 + b) * NPTS + x;
    float m = 3.0e38f;
#pragma unroll
    for (int c = 0; c < GYB; ++c)               // 8 loads from 2MB (L2/L3)
        m = fminf(m, p0[(size_t)c * NSLICE * NPTS]);

    // hx from the SAME bf16 rounding the MFMA B-side used: d = |xh - y|
    const float* xp = (dir ? P : T) + ((size_t)b * NPTS + x) * 3;
    float a0 = bf2f(bfr(xp[0]));
    float a1 = bf2f(bfr(xp[1]));
    float a2 = bf2f(bfr(xp[2]));
    float hx = 0.5f * (a0 * a0 + a1 * a1 + a2 * a2);
    float d  = sqrtf(fmaxf(2.0f * (hx + m), 0.0f));
    if (dir) out[1 + idx] = d;                  // mins_seeds

#pragma unroll
    for (int off = 32; off > 0; off >>= 1)
        d += __shfl_down(d, off, 64);
    if ((threadIdx.x & 63) == 0) partials[i >> 6] = d;
}

// Single-wave final reduction (separate launch: kernel boundary is the only
// cheap reliable cross-XCD flush — R14/R19 lessons).
__global__ void scalar_kernel(const float* __restrict__ partials,
                              float* __restrict__ out) {
    int t = threadIdx.x;                        // 64 threads
    float s = 0.0f;
#pragma unroll
    for (int k = 0; k < NPARTIAL / 64; ++k)
        s += partials[t + 64 * k];              // coalesced
#pragma unroll
    for (int off = 32; off > 0; off >>= 1)
        s += __shfl_down(s, off, 64);
    if (t == 0) out[0] = s * (1.0f / (float)TOTPTS);
}

extern "C" void kernel_launch(void* const* d_in, const int* in_sizes, int n_in,
                              void* d_out, int out_size, void* d_ws, size_t ws_size,
                              hipStream_t stream) {
    const float* truep = (const float*)d_in[0];   // [4, 8192, 3] fp32
    const float* predp = (const float*)d_in[1];   // [4, 8192, 3] fp32
    float* out = (float*)d_out;                   // [1 + 32768] fp32

    float* ws2      = (float*)d_ws;               // 2 MB chunk mins (no init)
    float* partials = ws2 + WS2_FLOATS;           // 1024 floats (write-first)
    bf16x4* frag    = (bf16x4*)((float*)d_ws + FRAG_OFF_FLOATS);  // 1 MB @ +4MB

    prep_frags<<<dim3(NPTS / TPB, NSLICE), TPB, 0, stream>>>(truep, predp, frag);

    dim3 grid(GX1, GYB, 2 * NB);                  // (128, 8, 8) = 8192 blocks
    nnmin_mfma1w<<<grid, 64, 0, stream>>>(truep, predp, frag, ws2);

    finalize_kernel<<<(2 * TOTPTS) / TPB, TPB, 0, stream>>>(
        ws2, truep, predp, out, partials);
    scalar_kernel<<<1, 64, 0, stream>>>(partials, out);
}